// Round 11
// baseline (2207.816 us; speedup 1.0000x reference)
//
#include <hip/hip_runtime.h>

#define D 64
#define TSCAN 1024

typedef unsigned int   u32;
typedef unsigned short u16;

__device__ __forceinline__ float bcastf(float v, int l) {
    return __uint_as_float(__builtin_amdgcn_readlane(__float_as_uint(v), l));
}
__device__ __forceinline__ u32 f2bf(float f) {
    u32 u = __float_as_uint(f);
    return (u + 0x7fffu + ((u >> 16) & 1u)) >> 16;
}
__device__ __forceinline__ float bflo(u32 v) { return __uint_as_float(v << 16); }
__device__ __forceinline__ float bfhi(u32 v) { return __uint_as_float(v & 0xffff0000u); }

// ---------- generic histogram ----------
__global__ void __launch_bounds__(256) hist_kernel(
    const int* __restrict__ idx, int* __restrict__ cnt, int E)
{
    int t = blockIdx.x * blockDim.x + threadIdx.x;
    int st = gridDim.x * blockDim.x;
    for (int e = t; e < E; e += st) atomicAdd(&cnt[idx[e]], 1);
}

__global__ void __launch_bounds__(TSCAN) partial_kernel(
    const int* __restrict__ cnt, int* __restrict__ partials, int n)
{
    __shared__ int red[TSCAN];
    int i = blockIdx.x * TSCAN + threadIdx.x;
    red[threadIdx.x] = (i < n) ? cnt[i] : 0;
    __syncthreads();
    for (int off = TSCAN / 2; off > 0; off >>= 1) {
        if (threadIdx.x < off) red[threadIdx.x] += red[threadIdx.x + off];
        __syncthreads();
    }
    if (threadIdx.x == 0) partials[blockIdx.x] = red[0];
}

__global__ void __launch_bounds__(128) scanp_kernel(
    const int* __restrict__ partials, int* __restrict__ blockoff, int nb)
{
    __shared__ int s[128];
    int t = threadIdx.x;
    int orig = (t < nb) ? partials[t] : 0;
    s[t] = orig;
    __syncthreads();
    for (int off = 1; off < 128; off <<= 1) {
        int v = (t >= off) ? s[t - off] : 0;
        __syncthreads();
        s[t] += v;
        __syncthreads();
    }
    if (t < nb) blockoff[t] = s[t] - orig;   // exclusive
}

__global__ void __launch_bounds__(TSCAN) rowptr_kernel(
    const int* __restrict__ cnt, const int* __restrict__ blockoff,
    int* __restrict__ rowptr, int* __restrict__ cursor, int n)
{
    __shared__ int s[TSCAN];
    int b = blockIdx.x;
    int i = b * TSCAN + threadIdx.x;
    int v = (i < n) ? cnt[i] : 0;
    s[threadIdx.x] = v;
    __syncthreads();
    for (int off = 1; off < TSCAN; off <<= 1) {
        int x = (threadIdx.x >= off) ? s[threadIdx.x - off] : 0;
        __syncthreads();
        s[threadIdx.x] += x;
        __syncthreads();
    }
    if (i < n) {
        int excl = blockoff[b] + s[threadIdx.x] - v;
        rowptr[i] = excl;
        cursor[i] = excl;
        if (i == n - 1) rowptr[n] = excl + v;
    }
}

// CSC fill: edges sorted by src; store dst
__global__ void __launch_bounds__(256) fillv_kernel(
    const int* __restrict__ src, const int* __restrict__ dst,
    int* __restrict__ cursor, int* __restrict__ adjdst, int E)
{
    int t = blockIdx.x * blockDim.x + threadIdx.x;
    int st = gridDim.x * blockDim.x;
    for (int e = t; e < E; e += st) {
        int p = atomicAdd(&cursor[src[e]], 1);
        adjdst[p] = dst[e];
    }
}

// ---------- scatter: wave per src, sequential row read, atomic adds ----------
__global__ void __launch_bounds__(256) scatter_kernel(
    const float* __restrict__ x,        // [n, 64]
    const int*   __restrict__ rowptr_s, // [n+1] (src-side CSR)
    const int*   __restrict__ adjdst,   // [E] dst sorted by src
    float*       __restrict__ agg,      // [n, 64] pre-zeroed
    int n)
{
    int lane = threadIdx.x & 63;
    int wid  = (blockIdx.x * blockDim.x + threadIdx.x) >> 6;
    int nw   = (gridDim.x * blockDim.x) >> 6;
    for (int s = wid; s < n; s += nw) {
        int ro = rowptr_s[s], re = rowptr_s[s + 1];
        if (ro == re) continue;
        float v = x[(size_t)s * D + lane];   // one sequential 256B row read
        int i = ro;
        for (; i + 4 <= re; i += 4) {
            int d0 = adjdst[i+0], d1 = adjdst[i+1], d2 = adjdst[i+2], d3 = adjdst[i+3];
            atomicAdd(&agg[(size_t)d0 * D + lane], v);
            atomicAdd(&agg[(size_t)d1 * D + lane], v);
            atomicAdd(&agg[(size_t)d2 * D + lane], v);
            atomicAdd(&agg[(size_t)d3 * D + lane], v);
        }
        for (; i < re; ++i)
            atomicAdd(&agg[(size_t)adjdst[i] * D + lane], v);
    }
}

// ---------- concat-linear (+ optional head), pure streaming ----------
// Wave per node; lane j owns output channel j. W transposed in 32KB LDS;
// bias + head params in registers; Wc1 packed bf16 in 4KB LDS (HEAD).
template <bool HEAD>
__global__ void __launch_bounds__(512, 8) mlp_kernel(
    const float* __restrict__ x,       // [n, 64] self
    const float* __restrict__ agg,     // [n, 64] neighbor sums
    const int*   __restrict__ degi,    // [n] dst in-degree
    const float* __restrict__ W,       // [64, 128] row-major
    const float* __restrict__ b,       // [64]
    const float* __restrict__ Wc1,     // [32, 64]  (HEAD only)
    const float* __restrict__ bc1,     // [32]
    const float* __restrict__ Wc2,     // [2, 32]
    const float* __restrict__ bc2,     // [2]
    float*       __restrict__ out,     // HEAD ? [n,2] : [n,64]
    int n)
{
    extern __shared__ float smem[];
    float4* Wt4 = (float4*)smem;               // 8192 floats = 32KB
    float*  Wt  = smem;
    u32*    wc1p = (u32*)(smem + 8192);        // 1024 u32 = 4KB (HEAD)

    for (int d = threadIdx.x; d < 64 * 128; d += blockDim.x) {
        int k4 = d >> 8;
        int j  = (d >> 2) & 63;
        int kk = d & 3;
        Wt[d] = W[j * 128 + k4 * 4 + kk];
    }
    if (HEAD) {
        for (int d = threadIdx.x; d < 32 * 32; d += blockDim.x) {
            int k2 = d >> 5, l = d & 31;
            wc1p[d] = f2bf(Wc1[l * 64 + 2 * k2]) | (f2bf(Wc1[l * 64 + 2 * k2 + 1]) << 16);
        }
    }
    __syncthreads();

    int lane = threadIdx.x & 63;
    int l    = lane & 31;
    float bj = b[lane];
    float bc1r = 0.f, w2a = 0.f, w2b = 0.f, bc20 = 0.f, bc21 = 0.f;
    if (HEAD) {
        bc1r = bc1[l];
        w2a  = Wc2[l];
        w2b  = Wc2[32 + l];
        bc20 = bc2[0];
        bc21 = bc2[1];
    }

    int wid  = (blockIdx.x * blockDim.x + threadIdx.x) >> 6;
    int nw   = (gridDim.x * blockDim.x) >> 6;
    for (int node = wid; node < n; node += nw) {
        float xv = x[(size_t)node * D + lane];
        float dg = fmaxf((float)degi[node], 1.0f);
        float av = agg[(size_t)node * D + lane] / dg;

        float sum = bj;
        #pragma unroll
        for (int k4 = 0; k4 < 16; ++k4) {
            float4 w = Wt4[k4 * 64 + lane];
            sum = fmaf(bcastf(xv, 4 * k4 + 0), w.x, sum);
            sum = fmaf(bcastf(xv, 4 * k4 + 1), w.y, sum);
            sum = fmaf(bcastf(xv, 4 * k4 + 2), w.z, sum);
            sum = fmaf(bcastf(xv, 4 * k4 + 3), w.w, sum);
        }
        #pragma unroll
        for (int k4 = 16; k4 < 32; ++k4) {
            float4 w = Wt4[k4 * 64 + lane];
            int kk = 4 * (k4 - 16);
            sum = fmaf(bcastf(av, kk + 0), w.x, sum);
            sum = fmaf(bcastf(av, kk + 1), w.y, sum);
            sum = fmaf(bcastf(av, kk + 2), w.z, sum);
            sum = fmaf(bcastf(av, kk + 3), w.w, sum);
        }
        float x2 = fmaxf(sum, 0.0f);   // ReLU; lane j holds output channel j

        if (!HEAD) {
            out[(size_t)node * D + lane] = x2;
        } else {
            float h = bc1r;
            #pragma unroll
            for (int k2 = 0; k2 < 32; ++k2) {
                u32 wp = wc1p[k2 * 32 + l];
                h = fmaf(bcastf(x2, 2 * k2 + 0), bflo(wp), h);
                h = fmaf(bcastf(x2, 2 * k2 + 1), bfhi(wp), h);
            }
            h = fmaxf(h, 0.0f);
            float p0 = (lane < 32) ? h * w2a : 0.0f;
            float p1 = (lane < 32) ? h * w2b : 0.0f;
            #pragma unroll
            for (int off = 1; off < 64; off <<= 1) {
                p0 += __shfl_xor(p0, off, 64);
                p1 += __shfl_xor(p1, off, 64);
            }
            if (lane == 0) {
                out[(size_t)node * 2 + 0] = p0 + bc20;
                out[(size_t)node * 2 + 1] = p1 + bc21;
            }
        }
    }
}

extern "C" void kernel_launch(void* const* d_in, const int* in_sizes, int n_in,
                              void* d_out, int out_size, void* d_ws, size_t ws_size,
                              hipStream_t stream)
{
    const float* feat = (const float*)d_in[0];
    const int*   eidx = (const int*)d_in[1];
    const float* W1   = (const float*)d_in[2];
    const float* b1   = (const float*)d_in[3];
    const float* W2   = (const float*)d_in[4];
    const float* b2   = (const float*)d_in[5];
    const float* Wc1  = (const float*)d_in[6];
    const float* bc1  = (const float*)d_in[7];
    const float* Wc2  = (const float*)d_in[8];
    const float* bc2  = (const float*)d_in[9];

    int n = in_sizes[0] / D;    // 100000
    int E = in_sizes[1] / 2;    // 1600000
    const int* src = eidx;
    const int* dst = eidx + E;

    // workspace layout (words) ~59MB
    int*   cnt_s    = (int*)d_ws;                 // [n]   src out-degree
    int*   partials = cnt_s + n;                  // [128]
    int*   blockoff = partials + 128;             // [128]
    int*   rowptr_s = blockoff + 128;             // [n+1]
    int*   cursor_s = rowptr_s + n + 1;           // [n]
    int*   degi     = cursor_s + n;               // [n]   dst in-degree
    int*   adjdst   = degi + n;                   // [E]
    float* agg      = (float*)(adjdst + E);       // [n*64]
    float* x1       = agg + (size_t)n * D;        // [n*64]

    int nb = (n + TSCAN - 1) / TSCAN;             // 98

    // src-sorted edge structure (CSC) + dst degree histogram
    hipMemsetAsync(cnt_s, 0, (size_t)n * sizeof(int), stream);
    hipMemsetAsync(degi, 0, (size_t)n * sizeof(int), stream);
    hist_kernel<<<6250, 256, 0, stream>>>(src, cnt_s, E);
    hist_kernel<<<6250, 256, 0, stream>>>(dst, degi, E);
    partial_kernel<<<nb, TSCAN, 0, stream>>>(cnt_s, partials, n);
    scanp_kernel<<<1, 128, 0, stream>>>(partials, blockoff, nb);
    rowptr_kernel<<<nb, TSCAN, 0, stream>>>(cnt_s, blockoff, rowptr_s, cursor_s, n);
    fillv_kernel<<<6250, 256, 0, stream>>>(src, dst, cursor_s, adjdst, E);

    // Layer 1: agg = sum_{e:src->dst} feat[src]; x1 = relu([feat|agg/deg]@W1+b1)
    hipMemsetAsync(agg, 0, (size_t)n * D * sizeof(float), stream);
    scatter_kernel<<<2048, 256, 0, stream>>>(feat, rowptr_s, adjdst, agg, n);
    mlp_kernel<false><<<1024, 512, 32768, stream>>>(
        feat, agg, degi, W1, b1,
        nullptr, nullptr, nullptr, nullptr, x1, n);

    // Layer 2 + head
    hipMemsetAsync(agg, 0, (size_t)n * D * sizeof(float), stream);
    scatter_kernel<<<2048, 256, 0, stream>>>(x1, rowptr_s, adjdst, agg, n);
    mlp_kernel<true><<<1024, 512, 32768 + 4096, stream>>>(
        x1, agg, degi, W2, b2,
        Wc1, bc1, Wc2, bc2, (float*)d_out, n);
}